// Round 12
// baseline (386.487 us; speedup 1.0000x reference)
//
#include <hip/hip_runtime.h>

// Problem constants
#define NT   365
#define NS   256
#define NH   256
#define NG   32
#define NR   16
#define HID  256
#define NX   38           // 6 + NG
#define M_   (NT*NS)      // 93440
#define TOUT (NT-NR+1)    // 350

typedef __attribute__((ext_vector_type(8))) short short8;
typedef __attribute__((ext_vector_type(4))) short short4v;
typedef __attribute__((ext_vector_type(4))) float floatx4;
typedef unsigned short u16;

__device__ __forceinline__ u16 f2bf(float f) {
    unsigned u = __float_as_uint(f);
    u = (u + 0x7FFFu + ((u >> 16) & 1u)) >> 16;   // RNE
    return (u16)u;
}
__device__ __forceinline__ float sigmoidf_(float x) { return 1.f / (1.f + __expf(-x)); }

// Fragment-tile layout (R17-proven): a 16x32 bf16 MFMA tile is stored as
// 64 lanes x 8 u16 contiguous (1 KB). Element (r, c) lives at
// lane = (r&15) | (((c&31)>>3)<<4), pos = c&7.
// R18: h1b tiles are (s, t-tile): row = t&15, tile idx = (s*23 + tt)*8 + kg
//      (s-stride = 23*8*512 = 94208 u16).
//      w2tT tiles unchanged: tile idx = ntile*8 + kg, ntile = n>>4.

// ---------------- k_prep: pre(365) + cvtT3(416) + mlp1(32) = 813 blocks ----------------
__global__ __launch_bounds__(256) void k_prep(const float* __restrict__ x,
                                              float* __restrict__ psT, float* __restrict__ plcT,
                                              float* __restrict__ e2T, float* __restrict__ out,
                                              const float* __restrict__ tw2, u16* __restrict__ w2tT,
                                              const float* __restrict__ fw2, u16* __restrict__ w2tW,
                                              const float* __restrict__ rw2, u16* __restrict__ w2tR,
                                              const float* __restrict__ xc,
                                              const float* __restrict__ wW, const float* __restrict__ bW,
                                              const float* __restrict__ wR, const float* __restrict__ bR,
                                              u16* __restrict__ h1W, u16* __restrict__ h1R) {
    int bx = blockIdx.x, tid = threadIdx.x;
    if (bx < 365) {
        // ---- pre body (+ zero out); outputs transposed [s][368] for fused scan ----
        int m = bx * 256 + tid;          // t = bx, s = tid
        if (m < TOUT*NS) out[m] = 0.f;
        float P  = x[m*6+0], E = x[m*6+1], T1 = x[m*6+2], T2 = x[m*6+3];
        float vf;
        if (T2 <= 0.f)      vf = 1.f;
        else if (T1 >= 0.f) vf = 0.f;
        else {
            float ratio = (T1 + T2) / (T2 - T1);
            ratio = fminf(fmaxf(ratio, -1.f), 1.f);
            vf = acosf(ratio) * (1.f / 3.1415f);
        }
        psT[tid*368 + bx]  = P * vf;
        plcT[tid*368 + bx] = P * (1.f - vf);
        e2T[tid*368 + bx]  = 2.f * E;
    } else if (bx < 781) {
        // ---- cvtT3 body ----
        __shared__ u16 tile[64][65];
        int i2 = bx - 365;
        int bn_ = i2 % 104, bk = i2 / 104;
        const float* w; u16* wt; int N, bn; bool frag;
        if (bn_ < 12)      { w = tw2; wt = w2tT; N = 768;  bn = bn_;      frag = true;  }
        else if (bn_ < 40) { w = fw2; wt = w2tW; N = 1792; bn = bn_ - 12; frag = false; }
        else               { w = rw2; wt = w2tR; N = 4096; bn = bn_ - 40; frag = false; }
        for (int i = tid; i < 64*64; i += 256) {
            int kk = i >> 6, nn = i & 63;
            tile[nn][kk] = f2bf(w[(size_t)(bk*64 + kk)*N + bn*64 + nn]);
        }
        __syncthreads();
        for (int i = tid; i < 64*64; i += 256) {
            int nn = i >> 6, kk = i & 63;
            int n = bn*64 + nn, k = bk*64 + kk;
            if (frag) {
                int ntile = n >> 4, kg = k >> 5;
                int lane2 = (n & 15) | (((k & 31) >> 3) << 4);
                wt[(((size_t)(ntile*8 + kg)) << 9) + (lane2 << 3) + (k & 7)] = tile[nn][kk];
            } else {
                wt[(size_t)n*256 + k] = tile[nn][kk];
            }
        }
    } else {
        // ---- mlp1 body ----
        int b = bx - 781;                       // 0..31: net*16 + grp
        int net = b >> 4, grp = b & 15;
        const float* w1 = net ? wR : wW;
        const float* b1 = net ? bR : bW;
        u16* o = net ? h1R : h1W;
        int s0 = grp * 16, j = tid;
        __shared__ float xs1[16][NG];
        for (int i = j; i < 16*NG; i += 256) xs1[i >> 5][i & 31] = xc[s0*NG + i];
        __syncthreads();
        float acc[16];
        float bb = b1[j];
#pragma unroll
        for (int si = 0; si < 16; ++si) acc[si] = bb;
        for (int g = 0; g < NG; ++g) {
            float w = w1[g*HID + j];
#pragma unroll
            for (int si = 0; si < 16; ++si) acc[si] += xs1[si][g] * w;
        }
#pragma unroll
        for (int si = 0; si < 16; ++si) o[(s0 + si)*256 + j] = f2bf(tanhf(acc[si]));
    }
}

// ---------------- k_mid: gemmS<0>(28) + gemmS<1>(64) + fcT1(2944) = 3036 blocks ----------------
// R25: fcT1 retiled thread = (8 rows x 4 cols). LDS reads/wave drop 1216
// (scalar broadcast b32, ~100us of LDS-pipe time chip-wide) -> ~90 (72 b128
// broadcast + 16 b32 remainder). w loads become coalesced float4. Accumulation
// order over g unchanged (ascending) -> identical numerics. smem union (R24).
__global__ __launch_bounds__(256) void k_mid(const u16* __restrict__ h1W, const u16* __restrict__ w2tW,
                                             const float* __restrict__ fb2, float* __restrict__ wlog,
                                             const u16* __restrict__ h1R, const u16* __restrict__ w2tR,
                                             const float* __restrict__ rb2, float* __restrict__ rbuf,
                                             const float* __restrict__ x, const float* __restrict__ xc,
                                             const float* __restrict__ tw1, const float* __restrict__ tb1,
                                             u16* __restrict__ h1b) {
    __shared__ __align__(16) unsigned char smem[16896];   // union: gemmS As+Bs / fcT1 xs->hs
    int bx = blockIdx.x, tid = threadIdx.x;
    if (bx < 92) {
        // ---- gemmS body (mode 0: bx<28, mode 1: else) ----
        int mode, bm, bn, Nn;
        const u16 *A, *B; const float* bias; float* outp;
        if (bx < 28) { mode = 0; bm = bx % 2;        bn = bx / 2;        Nn = 1792; A = h1W; B = w2tW; bias = fb2; outp = wlog; }
        else         { mode = 1; bm = (bx - 28) % 2; bn = (bx - 28) / 2; Nn = 4096; A = h1R; B = w2tR; bias = rb2; outp = rbuf; }
        u16* As = (u16*)smem;              // 8 KB
        u16* Bs = (u16*)(smem + 8192);     // 8 KB
        int wave = tid >> 6, lane = tid & 63;
        floatx4 acc[4][4];
#pragma unroll
        for (int i = 0; i < 4; ++i)
#pragma unroll
            for (int jj = 0; jj < 4; ++jj) acc[i][jj] = (floatx4)(0.f);
        int m0 = bm*128, n0 = bn*128;
        int rA = tid >> 2, cA = (tid & 3) * 8;
        int wm = (wave >> 1)*64, wn = (wave & 1)*64, lr = lane & 15, lq = lane >> 4;
        for (int k0 = 0; k0 < 256; k0 += 32) {
            short8 a0  = *(const short8*)(A + (m0 + rA     )*256 + k0 + cA);
            short8 a1  = *(const short8*)(A + (m0 + rA + 64)*256 + k0 + cA);
            short8 bv0 = *(const short8*)(B + (n0 + rA     )*256 + k0 + cA);
            short8 bv1 = *(const short8*)(B + (n0 + rA + 64)*256 + k0 + cA);
            __syncthreads();
            *(short8*)(As + rA*32 + cA)        = a0;
            *(short8*)(As + (rA + 64)*32 + cA) = a1;
            *(short8*)(Bs + rA*32 + cA)        = bv0;
            *(short8*)(Bs + (rA + 64)*32 + cA) = bv1;
            __syncthreads();
            short8 af[4], bf[4];
#pragma unroll
            for (int i = 0; i < 4; ++i)
                af[i] = *(const short8*)(As + (wm + i*16 + lr)*32 + lq*8);
#pragma unroll
            for (int jj = 0; jj < 4; ++jj)
                bf[jj] = *(const short8*)(Bs + (wn + jj*16 + lr)*32 + lq*8);
#pragma unroll
            for (int i = 0; i < 4; ++i)
#pragma unroll
                for (int jj = 0; jj < 4; ++jj)
                    acc[i][jj] = __builtin_amdgcn_mfma_f32_16x16x32_bf16(af[i], bf[jj], acc[i][jj], 0, 0, 0);
        }
#pragma unroll
        for (int jj = 0; jj < 4; ++jj) {
            int n_glob = n0 + wn + jj*16 + lr;
            float bv = bias[n_glob];
            int hg = (n0 + wn + jj*16) >> 4;
#pragma unroll
            for (int i = 0; i < 4; ++i) {
#pragma unroll
                for (int rr = 0; rr < 4; ++rr) {
                    int m = m0 + wm + i*16 + lq*4 + rr;
                    float v = acc[i][jj][rr] + bv;
                    if (mode == 0) {
                        outp[(size_t)m*Nn + n_glob] = v;
                    } else {
                        v = fmaxf(v, 0.f);
                        float mx = v;
#pragma unroll
                        for (int d = 1; d < 16; d <<= 1) mx = fmaxf(mx, __shfl_xor(mx, d, 64));
                        float e = __expf(v - mx);
                        float sm = e;
#pragma unroll
                        for (int d = 1; d < 16; d <<= 1) sm += __shfl_xor(sm, d, 64);
                        outp[(size_t)m*4096 + hg*16 + lr] = e / sm;
                    }
                }
            }
        }
    } else {
        // ---- fcT1 body: (8 row x 4 col)/thread register tile, b128 LDS reads ----
        int m0 = (bx - 92) * 32;           // 32 consecutive m = fixed t, 32 consecutive s
        int jg = tid & 63;                 // j-group: cols j0..j0+3
        int rg = tid >> 6;                 // rr-group: rows rr0..rr0+7
        int j0 = jg * 4;
        int rr0 = rg * 8;
        float (*xs)[40] = (float (*)[40])smem;      // 5,120 B (MAC phase; pad cols 38,39 = 0)
        for (int idx = tid; idx < 32*40; idx += 256) {
            int rr = idx / 40, c = idx % 40;
            int m = m0 + rr;
            int mc = m < M_ ? m : M_ - 1;
            int s = mc & (NS - 1);
            float v;
            if (c < 6)        v = x[mc*6 + c];
            else if (c < NX)  v = xc[s*NG + (c - 6)];
            else              v = 0.f;
            xs[rr][c] = v;
        }
        __syncthreads();
        floatx4 bv = *(const floatx4*)(tb1 + j0);
        float acc[8][4];
#pragma unroll
        for (int rp = 0; rp < 8; ++rp)
#pragma unroll
            for (int jj = 0; jj < 4; ++jj) acc[rp][jj] = bv[jj];
        // g = 0..35 in chunks of 4 (ascending order preserved)
        for (int gc = 0; gc < 9; ++gc) {
            floatx4 wv[4];
#pragma unroll
            for (int gq = 0; gq < 4; ++gq)
                wv[gq] = *(const floatx4*)(tw1 + (gc*4 + gq)*HID + j0);
#pragma unroll
            for (int rp = 0; rp < 8; ++rp) {
                floatx4 xv = *(const floatx4*)(&xs[rr0 + rp][gc*4]);
#pragma unroll
                for (int gq = 0; gq < 4; ++gq)
#pragma unroll
                    for (int jj = 0; jj < 4; ++jj)
                        acc[rp][jj] += xv[gq] * wv[gq][jj];
            }
        }
        // remainder g = 36, 37
#pragma unroll
        for (int g = 36; g < 38; ++g) {
            floatx4 wv = *(const floatx4*)(tw1 + g*HID + j0);
#pragma unroll
            for (int rp = 0; rp < 8; ++rp) {
                float xv = xs[rr0 + rp][g];
#pragma unroll
                for (int jj = 0; jj < 4; ++jj)
                    acc[rp][jj] += xv * wv[jj];
            }
        }
        __syncthreads();                    // xs reads done -> reuse smem as hs
        u16 (*hs)[264] = (u16 (*)[264])smem;                // 16,896 B (store phase)
#pragma unroll
        for (int rp = 0; rp < 8; ++rp) {
            short4v h4;
#pragma unroll
            for (int jj = 0; jj < 4; ++jj)
                h4[jj] = (short)f2bf(tanhf(acc[rp][jj]));
            *(short4v*)(&hs[rr0 + rp][j0]) = h4;
        }
        __syncthreads();
        // store phase (R21-proven): 1024 chunks of 16B
        int t_  = m0 >> 8;
        int tt_ = t_ >> 4, tr_ = t_ & 15;
        int s0_ = m0 & 255;
#pragma unroll
        for (int p = 0; p < 4; ++p) {
            int cid = p*256 + tid;
            int rr = cid >> 5, c = cid & 31;
            int kg = c >> 2, lh = c & 3;
            int jb = kg*32 + lh*8;
            short8 v = *(const short8*)(&hs[rr][jb]);
            *(short8*)(h1b + (size_t)(s0_ + rr)*94208
                       + (((size_t)tt_*8 + kg) << 9)
                       + ((tr_ | (lh << 4)) << 3)) = v;
        }
    }
}

// ---------------- k_post: fcw_post standalone (256 blocks) ----------------
__global__ __launch_bounds__(256) void k_post(const float* __restrict__ wlog,
                                              float* __restrict__ par) {
    __shared__ float red[256];
    int s = blockIdx.x, j = threadIdx.x;
    const float* L = wlog + (size_t)s*1792;
    float o0 = L[j], o1 = L[256+j], o2 = L[512+j], o3 = L[768+j],
          o4 = L[1024+j], o5 = L[1280+j], o6 = L[1536+j];
    red[j] = o6; __syncthreads();
    for (int st = 128; st > 0; st >>= 1) {
        if (j < st) red[j] = fmaxf(red[j], red[j+st]);
        __syncthreads();
    }
    float mx = red[0]; __syncthreads();
    float e = __expf(o6 - mx);
    red[j] = e; __syncthreads();
    for (int st = 128; st > 0; st >>= 1) {
        if (j < st) red[j] += red[j+st];
        __syncthreads();
    }
    float ga = e / red[0];
    int idx = s*NH + j;
    par[0*65536 + idx] = sigmoidf_(o0);
    par[1*65536 + idx] = sigmoidf_(o1);
    par[2*65536 + idx] = 0.1f * sigmoidf_(o2);
    par[3*65536 + idx] = sigmoidf_(o3);
    par[4*65536 + idx] = __expf(2.f * o4);
    par[5*65536 + idx] = fmaxf(o5, 0.f);
    par[6*65536 + idx] = ga;
}

// ---------------- k_scanfuse: producer-consumer wave-specialized (R22, kept) ----------------
__global__ __launch_bounds__(128, 2) void k_scanfuse(const u16* __restrict__ h1b,
                                                     const u16* __restrict__ w2t,
                                                     const float* __restrict__ b2,
                                                     const float* __restrict__ psT,
                                                     const float* __restrict__ plcT,
                                                     const float* __restrict__ e2T,
                                                     const float* __restrict__ par,
                                                     const float* __restrict__ r,
                                                     float* __restrict__ out) {
    int bx = blockIdx.x;
    int xcd = bx & 7, local = bx >> 3;
    int sgrp = xcd*8 + (local >> 4);
    int hb = local & 15;
    int tid = threadIdx.x;
    int wv = tid >> 6;                 // 0 = producer, 1 = consumer
    int lane = tid & 63;
    int h_idx = lane & 15, s_idx = lane >> 4;
    int s_g = sgrp*4 + s_idx, h_g = hb*16 + h_idx;
    int pidx = s_g*NH + h_g;

    __shared__ float s_ps[4][368];                 // 5.9 KB (consumer)
    __shared__ float xbuf[2][4*872];               // 27.9 KB (dbuf; stride-18 rows)
    __shared__ float sred[16*65];                  // 4.2 KB (consumer reduce)

    for (int i = tid; i < 4*368; i += 128) {
        int si = i / 368, t = i % 368;
        s_ps[si][t] = (t < NT) ? psT[(sgrp*4 + si)*368 + t] : 0.f;
    }

    short8 Bv[3][8];
    float bias0 = 0.f, bias1 = 0.f, bias2 = 0.f;
    const u16* Ab = h1b + (size_t)(sgrp*4)*94208 + (lane << 3);
    float kp = 0.f, ks_ = 0.f, kg = 0.f, gp = 0.f, gL = 0.f, qb = 0.f;
    float rt[NR];
    float Sf = 0.f, Ss = 0.f, Sg = 0.f;
    float qwin[16];
#pragma unroll
    for (int k = 0; k < 16; ++k) { qwin[k] = 0.f; rt[k] = 0.f; }

    if (wv == 0) {
#pragma unroll
        for (int sg2 = 0; sg2 < 3; ++sg2)
#pragma unroll
            for (int kgi = 0; kgi < 8; ++kgi)
                Bv[sg2][kgi] = *(const short8*)(w2t + (((size_t)((sg2*16 + hb)*8 + kgi)) << 9) + (lane << 3));
        bias0 = b2[0*256 + h_g]; bias1 = b2[1*256 + h_g]; bias2 = b2[2*256 + h_g];
    } else {
        kp = par[pidx]; ks_ = par[65536+pidx]; kg = par[2*65536+pidx];
        gp = par[3*65536+pidx]; gL = par[4*65536+pidx]; qb = par[5*65536+pidx];
        float ga = par[6*65536+pidx];
#pragma unroll
        for (int k = 0; k < NR; ++k) rt[k] = r[(size_t)pidx*NR + k] * ga;
    }

    auto produce = [&](int c, int b) {
        int tbase = c * 16;
        floatx4 acc[4][3];
#pragma unroll
        for (int si = 0; si < 4; ++si)
#pragma unroll
            for (int sg2 = 0; sg2 < 3; ++sg2) acc[si][sg2] = (floatx4)(0.f);
        const u16* An = Ab + (size_t)c*4096;
#pragma unroll
        for (int kgi = 0; kgi < 8; ++kgi) {
            short8 Avk[4];
#pragma unroll
            for (int si = 0; si < 4; ++si)
                Avk[si] = *(const short8*)(An + (size_t)si*94208 + kgi*512);
#pragma unroll
            for (int si = 0; si < 4; ++si)
#pragma unroll
                for (int sg2 = 0; sg2 < 3; ++sg2)
                    acc[si][sg2] = __builtin_amdgcn_mfma_f32_16x16x32_bf16(Avk[si], Bv[sg2][kgi], acc[si][sg2], 0, 0, 0);
        }
        float* xb = &xbuf[b][0];
#pragma unroll
        for (int si = 0; si < 4; ++si) {
            int sg = sgrp*4 + si;
            floatx4 plv = *(const floatx4*)(plcT + sg*368 + tbase + s_idx*4);
            floatx4 e2v = *(const floatx4*)(e2T  + sg*368 + tbase + s_idx*4);
#pragma unroll
            for (int rr = 0; rr < 4; ++rr) {
                int trow = s_idx*4 + rr;
                float v0 = acc[si][0][rr] + bias0;
                float v1 = acc[si][1][rr] + bias1;
                float v2 = acc[si][2][rr] + bias2;
                float pl = plv[rr] * fminf(fmaxf(v0*(1.f/3.f) + 0.5f, 0.f), 1.f);
                float ev = e2v[rr] * fmaxf(v1, 0.f);
                float fm = __expf(v2);
                xb[si*872 + 0*288 + trow*18 + h_idx] = pl;
                xb[si*872 + 1*288 + trow*18 + h_idx] = ev;
                xb[si*872 + 2*288 + trow*18 + h_idx] = fm;
            }
        }
    };

    __syncthreads();                    // s_ps staged
    if (wv == 0) produce(0, 0);         // prologue: chunk 0
    __syncthreads();

    for (int k = 0; k < 23; ++k) {
        if (wv == 0) {
            if (k < 22) produce(k + 1, (k + 1) & 1);
        } else {
            int tbase = k * 16;
            const float* xr = &xbuf[k & 1][0];
            float cv[16];
#pragma unroll
            for (int j = 0; j < 16; ++j) cv[j] = 0.f;
#pragma unroll
            for (int j = 0; j < 16; ++j) {
                int t = tbase + j;
                if (t < NT) {
                    float pl = xr[s_idx*872 + 0*288 + j*18 + h_idx];
                    float ev = xr[s_idx*872 + 1*288 + j*18 + h_idx];
                    float fm = xr[s_idx*872 + 2*288 + j*18 + h_idx];
                    float fs = s_ps[s_idx][t];
                    float qf = fminf(Sf + fs, fm);
                    Sf = fmaxf(Sf + fs - fm, 0.f);
                    float H = fmaxf(Ss + pl + qf - ev, 0.f);
                    float qp = fmaxf(kp * (H - gL), 0.f);
                    float qsa = ks_ * fminf(H, gL);
                    Ss = H - qp - qsa;
                    float qsg = qsa * gp;
                    float qs = qsa - qsg;
                    float qg = kg * (Sg + qsg) + qb;
                    Sg = (1.f - kg) * (Sg + qsg) - qb;
                    float q = qp + qs + qg;
                    qwin[j] = q;
                    if (t >= 15) {
                        float c = 0.f;
#pragma unroll
                        for (int kk = 0; kk < 16; ++kk) c += rt[kk] * qwin[(j + 1 + kk) & 15];
                        cv[j] = c;
                    }
                }
            }
#pragma unroll
            for (int j = 0; j < 16; ++j) sred[j*65 + lane] = cv[j];
            asm volatile("s_waitcnt lgkmcnt(0)" ::: "memory");
            {
                int j2 = lane & 15, q2 = lane >> 4;
                float p = 0.f;
#pragma unroll
                for (int i = 0; i < 16; ++i) p += sred[j2*65 + q2*16 + i];
                int tout = tbase + j2 - 15;
                if (tout >= 0 && tout < TOUT)
                    atomicAdd(out + tout*NS + sgrp*4 + q2, p);
            }
        }
        __syncthreads();                // xbuf[(k+1)&1] ready; xbuf[k&1] free
    }
}

// ---------------- launch ----------------
extern "C" void kernel_launch(void* const* d_in, const int* in_sizes, int n_in,
                              void* d_out, int out_size, void* d_ws, size_t ws_size,
                              hipStream_t stream) {
    const float* x   = (const float*)d_in[0];
    const float* xc  = (const float*)d_in[1];
    const float* fw1 = (const float*)d_in[2];
    const float* fb1 = (const float*)d_in[3];
    const float* fw2 = (const float*)d_in[4];
    const float* fb2 = (const float*)d_in[5];
    const float* tw1 = (const float*)d_in[6];
    const float* tb1 = (const float*)d_in[7];
    const float* tw2 = (const float*)d_in[8];
    const float* tb2 = (const float*)d_in[9];
    const float* rw1 = (const float*)d_in[10];
    const float* rb1 = (const float*)d_in[11];
    const float* rw2 = (const float*)d_in[12];
    const float* rb2 = (const float*)d_in[13];
    float* out = (float*)d_out;
    char* ws = (char*)d_ws;

    constexpr size_t OFF_PS    = 0;              //   376,832  [s][368] f32
    constexpr size_t OFF_PLC   = 376832;
    constexpr size_t OFF_E2    = 753664;
    constexpr size_t OFF_PAR   = 1130496;        // 1,835,008
    constexpr size_t OFF_R     = 2965504;        // 4,194,304
    constexpr size_t OFF_W2TT  = 7159808;        //   393,216
    constexpr size_t OFF_H1B   = 7553024;        // 48,234,496 (s-major frag tiles)
    constexpr size_t OFF_PC    = 55787520;       // overlays only now
    constexpr size_t OFF_WLOG  = 200491008;      // 1,835,008
    constexpr size_t OFF_W2TW  = OFF_PC + 0;
    constexpr size_t OFF_W2TR  = OFF_PC + 917504;
    constexpr size_t OFF_H1W   = OFF_PC + 3014656;
    constexpr size_t OFF_H1R   = OFF_PC + 3145728;

    float* psT   = (float*)(ws + OFF_PS);
    float* plcT  = (float*)(ws + OFF_PLC);
    float* e2T   = (float*)(ws + OFF_E2);
    float* par   = (float*)(ws + OFF_PAR);
    float* rbuf  = (float*)(ws + OFF_R);
    u16*   w2tT  = (u16*)(ws + OFF_W2TT);
    u16*   h1b   = (u16*)(ws + OFF_H1B);
    float* wlog  = (float*)(ws + OFF_WLOG);
    u16*   w2tW  = (u16*)(ws + OFF_W2TW);
    u16*   w2tR  = (u16*)(ws + OFF_W2TR);
    u16*   h1W   = (u16*)(ws + OFF_H1W);
    u16*   h1R   = (u16*)(ws + OFF_H1R);

    k_prep     <<<813, 256, 0, stream>>>(x, psT, plcT, e2T, out,
                                         tw2, w2tT, fw2, w2tW, rw2, w2tR,
                                         xc, fw1, fb1, rw1, rb1, h1W, h1R);
    k_mid      <<<3036, 256, 0, stream>>>(h1W, w2tW, fb2, wlog,
                                          h1R, w2tR, rb2, rbuf,
                                          x, xc, tw1, tb1, h1b);
    k_post     <<<256, 256, 0, stream>>>(wlog, par);
    k_scanfuse <<<1024, 128, 0, stream>>>(h1b, w2tT, tb2, psT, plcT, e2T, par, rbuf, out);
}

// Round 13
// 280.686 us; speedup vs baseline: 1.3769x; 1.3769x over previous
//
#include <hip/hip_runtime.h>

// Problem constants
#define NT   365
#define NS   256
#define NH   256
#define NG   32
#define NR   16
#define HID  256
#define NX   38           // 6 + NG
#define M_   (NT*NS)      // 93440
#define TOUT (NT-NR+1)    // 350

typedef __attribute__((ext_vector_type(8))) short short8;
typedef __attribute__((ext_vector_type(4))) short short4v;
typedef __attribute__((ext_vector_type(4))) float floatx4;
typedef unsigned short u16;

__device__ __forceinline__ u16 f2bf(float f) {
    unsigned u = __float_as_uint(f);
    u = (u + 0x7FFFu + ((u >> 16) & 1u)) >> 16;   // RNE
    return (u16)u;
}
__device__ __forceinline__ float sigmoidf_(float x) { return 1.f / (1.f + __expf(-x)); }

// Fragment-tile layout (R17-proven): a 16x32 bf16 MFMA tile is stored as
// 64 lanes x 8 u16 contiguous (1 KB). Element (r, c) lives at
// lane = (r&15) | (((c&31)>>3)<<4), pos = c&7.
// R18: h1b tiles are (s, t-tile): row = t&15, tile idx = (s*23 + tt)*8 + kg
//      (s-stride = 23*8*512 = 94208 u16).
//      w2tT tiles unchanged: tile idx = ntile*8 + kg, ntile = n>>4.

// ---------------- k_prep: pre(365) + cvtT3(416) + mlp1(32) = 813 blocks ----------------
__global__ __launch_bounds__(256) void k_prep(const float* __restrict__ x,
                                              float* __restrict__ psT, float* __restrict__ plcT,
                                              float* __restrict__ e2T, float* __restrict__ out,
                                              const float* __restrict__ tw2, u16* __restrict__ w2tT,
                                              const float* __restrict__ fw2, u16* __restrict__ w2tW,
                                              const float* __restrict__ rw2, u16* __restrict__ w2tR,
                                              const float* __restrict__ xc,
                                              const float* __restrict__ wW, const float* __restrict__ bW,
                                              const float* __restrict__ wR, const float* __restrict__ bR,
                                              u16* __restrict__ h1W, u16* __restrict__ h1R) {
    int bx = blockIdx.x, tid = threadIdx.x;
    if (bx < 365) {
        // ---- pre body (+ zero out); outputs transposed [s][368] for fused scan ----
        int m = bx * 256 + tid;          // t = bx, s = tid
        if (m < TOUT*NS) out[m] = 0.f;
        float P  = x[m*6+0], E = x[m*6+1], T1 = x[m*6+2], T2 = x[m*6+3];
        float vf;
        if (T2 <= 0.f)      vf = 1.f;
        else if (T1 >= 0.f) vf = 0.f;
        else {
            float ratio = (T1 + T2) / (T2 - T1);
            ratio = fminf(fmaxf(ratio, -1.f), 1.f);
            vf = acosf(ratio) * (1.f / 3.1415f);
        }
        psT[tid*368 + bx]  = P * vf;
        plcT[tid*368 + bx] = P * (1.f - vf);
        e2T[tid*368 + bx]  = 2.f * E;
    } else if (bx < 781) {
        // ---- cvtT3 body ----
        __shared__ u16 tile[64][65];
        int i2 = bx - 365;
        int bn_ = i2 % 104, bk = i2 / 104;
        const float* w; u16* wt; int N, bn; bool frag;
        if (bn_ < 12)      { w = tw2; wt = w2tT; N = 768;  bn = bn_;      frag = true;  }
        else if (bn_ < 40) { w = fw2; wt = w2tW; N = 1792; bn = bn_ - 12; frag = false; }
        else               { w = rw2; wt = w2tR; N = 4096; bn = bn_ - 40; frag = false; }
        for (int i = tid; i < 64*64; i += 256) {
            int kk = i >> 6, nn = i & 63;
            tile[nn][kk] = f2bf(w[(size_t)(bk*64 + kk)*N + bn*64 + nn]);
        }
        __syncthreads();
        for (int i = tid; i < 64*64; i += 256) {
            int nn = i >> 6, kk = i & 63;
            int n = bn*64 + nn, k = bk*64 + kk;
            if (frag) {
                int ntile = n >> 4, kg = k >> 5;
                int lane2 = (n & 15) | (((k & 31) >> 3) << 4);
                wt[(((size_t)(ntile*8 + kg)) << 9) + (lane2 << 3) + (k & 7)] = tile[nn][kk];
            } else {
                wt[(size_t)n*256 + k] = tile[nn][kk];
            }
        }
    } else {
        // ---- mlp1 body ----
        int b = bx - 781;                       // 0..31: net*16 + grp
        int net = b >> 4, grp = b & 15;
        const float* w1 = net ? wR : wW;
        const float* b1 = net ? bR : bW;
        u16* o = net ? h1R : h1W;
        int s0 = grp * 16, j = tid;
        __shared__ float xs1[16][NG];
        for (int i = j; i < 16*NG; i += 256) xs1[i >> 5][i & 31] = xc[s0*NG + i];
        __syncthreads();
        float acc[16];
        float bb = b1[j];
#pragma unroll
        for (int si = 0; si < 16; ++si) acc[si] = bb;
        for (int g = 0; g < NG; ++g) {
            float w = w1[g*HID + j];
#pragma unroll
            for (int si = 0; si < 16; ++si) acc[si] += xs1[si][g] * w;
        }
#pragma unroll
        for (int si = 0; si < 16; ++si) o[(s0 + si)*256 + j] = f2bf(tanhf(acc[si]));
    }
}

// ---------------- k_mid: gemmS<0>(28) + gemmS<1>(64) + fcT1(2944) = 3036 blocks ----------------
// R26: R25's (8x4)/thread fcT1 retile with the gc-loop pinned to unroll 1.
// R25's full unroll hoisted 36 float4 w-loads -> VGPR 256 + 64MB scratch
// spill (WRITE_SIZE 53->117MB) -> 191us. Per-iteration live set is now
// wv[4] (16) + xv (4) + acc (32) ~ 100 VGPR. LDS reads/wave stay ~90 vs the
// pre-R25 1216 broadcast b32. smem union (R24). Accumulation order unchanged.
__global__ __launch_bounds__(256) void k_mid(const u16* __restrict__ h1W, const u16* __restrict__ w2tW,
                                             const float* __restrict__ fb2, float* __restrict__ wlog,
                                             const u16* __restrict__ h1R, const u16* __restrict__ w2tR,
                                             const float* __restrict__ rb2, float* __restrict__ rbuf,
                                             const float* __restrict__ x, const float* __restrict__ xc,
                                             const float* __restrict__ tw1, const float* __restrict__ tb1,
                                             u16* __restrict__ h1b) {
    __shared__ __align__(16) unsigned char smem[16896];   // union: gemmS As+Bs / fcT1 xs->hs
    int bx = blockIdx.x, tid = threadIdx.x;
    if (bx < 92) {
        // ---- gemmS body (mode 0: bx<28, mode 1: else) ----
        int mode, bm, bn, Nn;
        const u16 *A, *B; const float* bias; float* outp;
        if (bx < 28) { mode = 0; bm = bx % 2;        bn = bx / 2;        Nn = 1792; A = h1W; B = w2tW; bias = fb2; outp = wlog; }
        else         { mode = 1; bm = (bx - 28) % 2; bn = (bx - 28) / 2; Nn = 4096; A = h1R; B = w2tR; bias = rb2; outp = rbuf; }
        u16* As = (u16*)smem;              // 8 KB
        u16* Bs = (u16*)(smem + 8192);     // 8 KB
        int wave = tid >> 6, lane = tid & 63;
        floatx4 acc[4][4];
#pragma unroll
        for (int i = 0; i < 4; ++i)
#pragma unroll
            for (int jj = 0; jj < 4; ++jj) acc[i][jj] = (floatx4)(0.f);
        int m0 = bm*128, n0 = bn*128;
        int rA = tid >> 2, cA = (tid & 3) * 8;
        int wm = (wave >> 1)*64, wn = (wave & 1)*64, lr = lane & 15, lq = lane >> 4;
        for (int k0 = 0; k0 < 256; k0 += 32) {
            short8 a0  = *(const short8*)(A + (m0 + rA     )*256 + k0 + cA);
            short8 a1  = *(const short8*)(A + (m0 + rA + 64)*256 + k0 + cA);
            short8 bv0 = *(const short8*)(B + (n0 + rA     )*256 + k0 + cA);
            short8 bv1 = *(const short8*)(B + (n0 + rA + 64)*256 + k0 + cA);
            __syncthreads();
            *(short8*)(As + rA*32 + cA)        = a0;
            *(short8*)(As + (rA + 64)*32 + cA) = a1;
            *(short8*)(Bs + rA*32 + cA)        = bv0;
            *(short8*)(Bs + (rA + 64)*32 + cA) = bv1;
            __syncthreads();
            short8 af[4], bf[4];
#pragma unroll
            for (int i = 0; i < 4; ++i)
                af[i] = *(const short8*)(As + (wm + i*16 + lr)*32 + lq*8);
#pragma unroll
            for (int jj = 0; jj < 4; ++jj)
                bf[jj] = *(const short8*)(Bs + (wn + jj*16 + lr)*32 + lq*8);
#pragma unroll
            for (int i = 0; i < 4; ++i)
#pragma unroll
                for (int jj = 0; jj < 4; ++jj)
                    acc[i][jj] = __builtin_amdgcn_mfma_f32_16x16x32_bf16(af[i], bf[jj], acc[i][jj], 0, 0, 0);
        }
#pragma unroll
        for (int jj = 0; jj < 4; ++jj) {
            int n_glob = n0 + wn + jj*16 + lr;
            float bv = bias[n_glob];
            int hg = (n0 + wn + jj*16) >> 4;
#pragma unroll
            for (int i = 0; i < 4; ++i) {
#pragma unroll
                for (int rr = 0; rr < 4; ++rr) {
                    int m = m0 + wm + i*16 + lq*4 + rr;
                    float v = acc[i][jj][rr] + bv;
                    if (mode == 0) {
                        outp[(size_t)m*Nn + n_glob] = v;
                    } else {
                        v = fmaxf(v, 0.f);
                        float mx = v;
#pragma unroll
                        for (int d = 1; d < 16; d <<= 1) mx = fmaxf(mx, __shfl_xor(mx, d, 64));
                        float e = __expf(v - mx);
                        float sm = e;
#pragma unroll
                        for (int d = 1; d < 16; d <<= 1) sm += __shfl_xor(sm, d, 64);
                        outp[(size_t)m*4096 + hg*16 + lr] = e / sm;
                    }
                }
            }
        }
    } else {
        // ---- fcT1 body: (8 row x 4 col)/thread register tile, unroll-capped ----
        int m0 = (bx - 92) * 32;           // 32 consecutive m = fixed t, 32 consecutive s
        int jg = tid & 63;                 // j-group: cols j0..j0+3
        int rg = tid >> 6;                 // rr-group: rows rr0..rr0+7
        int j0 = jg * 4;
        int rr0 = rg * 8;
        float (*xs)[40] = (float (*)[40])smem;      // 5,120 B (MAC phase; pad cols 38,39 = 0)
        for (int idx = tid; idx < 32*40; idx += 256) {
            int rr = idx / 40, c = idx % 40;
            int m = m0 + rr;
            int mc = m < M_ ? m : M_ - 1;
            int s = mc & (NS - 1);
            float v;
            if (c < 6)        v = x[mc*6 + c];
            else if (c < NX)  v = xc[s*NG + (c - 6)];
            else              v = 0.f;
            xs[rr][c] = v;
        }
        __syncthreads();
        floatx4 bv = *(const floatx4*)(tb1 + j0);
        float acc[8][4];
#pragma unroll
        for (int rp = 0; rp < 8; ++rp)
#pragma unroll
            for (int jj = 0; jj < 4; ++jj) acc[rp][jj] = bv[jj];
        // g = 0..35 in chunks of 4 (ascending order preserved).
        // unroll 1: keeps only one iteration's wv[4]+xv live -> no VGPR blowup
        // (R25 lesson: full unroll hoisted 36 w-loads -> 256 VGPR + spills).
#pragma unroll 1
        for (int gc = 0; gc < 9; ++gc) {
            floatx4 wv[4];
#pragma unroll
            for (int gq = 0; gq < 4; ++gq)
                wv[gq] = *(const floatx4*)(tw1 + (gc*4 + gq)*HID + j0);
#pragma unroll
            for (int rp = 0; rp < 8; ++rp) {
                floatx4 xv = *(const floatx4*)(&xs[rr0 + rp][gc*4]);
#pragma unroll
                for (int gq = 0; gq < 4; ++gq)
#pragma unroll
                    for (int jj = 0; jj < 4; ++jj)
                        acc[rp][jj] += xv[gq] * wv[gq][jj];
            }
        }
        // remainder g = 36, 37
#pragma unroll 1
        for (int g = 36; g < 38; ++g) {
            floatx4 wv = *(const floatx4*)(tw1 + g*HID + j0);
#pragma unroll
            for (int rp = 0; rp < 8; ++rp) {
                float xv = xs[rr0 + rp][g];
#pragma unroll
                for (int jj = 0; jj < 4; ++jj)
                    acc[rp][jj] += xv * wv[jj];
            }
        }
        __syncthreads();                    // xs reads done -> reuse smem as hs
        u16 (*hs)[264] = (u16 (*)[264])smem;                // 16,896 B (store phase)
#pragma unroll
        for (int rp = 0; rp < 8; ++rp) {
            short4v h4;
#pragma unroll
            for (int jj = 0; jj < 4; ++jj)
                h4[jj] = (short)f2bf(tanhf(acc[rp][jj]));
            *(short4v*)(&hs[rr0 + rp][j0]) = h4;
        }
        __syncthreads();
        // store phase (R21-proven): 1024 chunks of 16B
        int t_  = m0 >> 8;
        int tt_ = t_ >> 4, tr_ = t_ & 15;
        int s0_ = m0 & 255;
#pragma unroll
        for (int p = 0; p < 4; ++p) {
            int cid = p*256 + tid;
            int rr = cid >> 5, c = cid & 31;
            int kg = c >> 2, lh = c & 3;
            int jb = kg*32 + lh*8;
            short8 v = *(const short8*)(&hs[rr][jb]);
            *(short8*)(h1b + (size_t)(s0_ + rr)*94208
                       + (((size_t)tt_*8 + kg) << 9)
                       + ((tr_ | (lh << 4)) << 3)) = v;
        }
    }
}

// ---------------- k_post: fcw_post standalone (256 blocks) ----------------
__global__ __launch_bounds__(256) void k_post(const float* __restrict__ wlog,
                                              float* __restrict__ par) {
    __shared__ float red[256];
    int s = blockIdx.x, j = threadIdx.x;
    const float* L = wlog + (size_t)s*1792;
    float o0 = L[j], o1 = L[256+j], o2 = L[512+j], o3 = L[768+j],
          o4 = L[1024+j], o5 = L[1280+j], o6 = L[1536+j];
    red[j] = o6; __syncthreads();
    for (int st = 128; st > 0; st >>= 1) {
        if (j < st) red[j] = fmaxf(red[j], red[j+st]);
        __syncthreads();
    }
    float mx = red[0]; __syncthreads();
    float e = __expf(o6 - mx);
    red[j] = e; __syncthreads();
    for (int st = 128; st > 0; st >>= 1) {
        if (j < st) red[j] += red[j+st];
        __syncthreads();
    }
    float ga = e / red[0];
    int idx = s*NH + j;
    par[0*65536 + idx] = sigmoidf_(o0);
    par[1*65536 + idx] = sigmoidf_(o1);
    par[2*65536 + idx] = 0.1f * sigmoidf_(o2);
    par[3*65536 + idx] = sigmoidf_(o3);
    par[4*65536 + idx] = __expf(2.f * o4);
    par[5*65536 + idx] = fmaxf(o5, 0.f);
    par[6*65536 + idx] = ga;
}

// ---------------- k_scanfuse: producer-consumer wave-specialized (R22, kept) ----------------
__global__ __launch_bounds__(128, 2) void k_scanfuse(const u16* __restrict__ h1b,
                                                     const u16* __restrict__ w2t,
                                                     const float* __restrict__ b2,
                                                     const float* __restrict__ psT,
                                                     const float* __restrict__ plcT,
                                                     const float* __restrict__ e2T,
                                                     const float* __restrict__ par,
                                                     const float* __restrict__ r,
                                                     float* __restrict__ out) {
    int bx = blockIdx.x;
    int xcd = bx & 7, local = bx >> 3;
    int sgrp = xcd*8 + (local >> 4);
    int hb = local & 15;
    int tid = threadIdx.x;
    int wv = tid >> 6;                 // 0 = producer, 1 = consumer
    int lane = tid & 63;
    int h_idx = lane & 15, s_idx = lane >> 4;
    int s_g = sgrp*4 + s_idx, h_g = hb*16 + h_idx;
    int pidx = s_g*NH + h_g;

    __shared__ float s_ps[4][368];                 // 5.9 KB (consumer)
    __shared__ float xbuf[2][4*872];               // 27.9 KB (dbuf; stride-18 rows)
    __shared__ float sred[16*65];                  // 4.2 KB (consumer reduce)

    for (int i = tid; i < 4*368; i += 128) {
        int si = i / 368, t = i % 368;
        s_ps[si][t] = (t < NT) ? psT[(sgrp*4 + si)*368 + t] : 0.f;
    }

    short8 Bv[3][8];
    float bias0 = 0.f, bias1 = 0.f, bias2 = 0.f;
    const u16* Ab = h1b + (size_t)(sgrp*4)*94208 + (lane << 3);
    float kp = 0.f, ks_ = 0.f, kg = 0.f, gp = 0.f, gL = 0.f, qb = 0.f;
    float rt[NR];
    float Sf = 0.f, Ss = 0.f, Sg = 0.f;
    float qwin[16];
#pragma unroll
    for (int k = 0; k < 16; ++k) { qwin[k] = 0.f; rt[k] = 0.f; }

    if (wv == 0) {
#pragma unroll
        for (int sg2 = 0; sg2 < 3; ++sg2)
#pragma unroll
            for (int kgi = 0; kgi < 8; ++kgi)
                Bv[sg2][kgi] = *(const short8*)(w2t + (((size_t)((sg2*16 + hb)*8 + kgi)) << 9) + (lane << 3));
        bias0 = b2[0*256 + h_g]; bias1 = b2[1*256 + h_g]; bias2 = b2[2*256 + h_g];
    } else {
        kp = par[pidx]; ks_ = par[65536+pidx]; kg = par[2*65536+pidx];
        gp = par[3*65536+pidx]; gL = par[4*65536+pidx]; qb = par[5*65536+pidx];
        float ga = par[6*65536+pidx];
#pragma unroll
        for (int k = 0; k < NR; ++k) rt[k] = r[(size_t)pidx*NR + k] * ga;
    }

    auto produce = [&](int c, int b) {
        int tbase = c * 16;
        floatx4 acc[4][3];
#pragma unroll
        for (int si = 0; si < 4; ++si)
#pragma unroll
            for (int sg2 = 0; sg2 < 3; ++sg2) acc[si][sg2] = (floatx4)(0.f);
        const u16* An = Ab + (size_t)c*4096;
#pragma unroll
        for (int kgi = 0; kgi < 8; ++kgi) {
            short8 Avk[4];
#pragma unroll
            for (int si = 0; si < 4; ++si)
                Avk[si] = *(const short8*)(An + (size_t)si*94208 + kgi*512);
#pragma unroll
            for (int si = 0; si < 4; ++si)
#pragma unroll
                for (int sg2 = 0; sg2 < 3; ++sg2)
                    acc[si][sg2] = __builtin_amdgcn_mfma_f32_16x16x32_bf16(Avk[si], Bv[sg2][kgi], acc[si][sg2], 0, 0, 0);
        }
        float* xb = &xbuf[b][0];
#pragma unroll
        for (int si = 0; si < 4; ++si) {
            int sg = sgrp*4 + si;
            floatx4 plv = *(const floatx4*)(plcT + sg*368 + tbase + s_idx*4);
            floatx4 e2v = *(const floatx4*)(e2T  + sg*368 + tbase + s_idx*4);
#pragma unroll
            for (int rr = 0; rr < 4; ++rr) {
                int trow = s_idx*4 + rr;
                float v0 = acc[si][0][rr] + bias0;
                float v1 = acc[si][1][rr] + bias1;
                float v2 = acc[si][2][rr] + bias2;
                float pl = plv[rr] * fminf(fmaxf(v0*(1.f/3.f) + 0.5f, 0.f), 1.f);
                float ev = e2v[rr] * fmaxf(v1, 0.f);
                float fm = __expf(v2);
                xb[si*872 + 0*288 + trow*18 + h_idx] = pl;
                xb[si*872 + 1*288 + trow*18 + h_idx] = ev;
                xb[si*872 + 2*288 + trow*18 + h_idx] = fm;
            }
        }
    };

    __syncthreads();                    // s_ps staged
    if (wv == 0) produce(0, 0);         // prologue: chunk 0
    __syncthreads();

    for (int k = 0; k < 23; ++k) {
        if (wv == 0) {
            if (k < 22) produce(k + 1, (k + 1) & 1);
        } else {
            int tbase = k * 16;
            const float* xr = &xbuf[k & 1][0];
            float cv[16];
#pragma unroll
            for (int j = 0; j < 16; ++j) cv[j] = 0.f;
#pragma unroll
            for (int j = 0; j < 16; ++j) {
                int t = tbase + j;
                if (t < NT) {
                    float pl = xr[s_idx*872 + 0*288 + j*18 + h_idx];
                    float ev = xr[s_idx*872 + 1*288 + j*18 + h_idx];
                    float fm = xr[s_idx*872 + 2*288 + j*18 + h_idx];
                    float fs = s_ps[s_idx][t];
                    float qf = fminf(Sf + fs, fm);
                    Sf = fmaxf(Sf + fs - fm, 0.f);
                    float H = fmaxf(Ss + pl + qf - ev, 0.f);
                    float qp = fmaxf(kp * (H - gL), 0.f);
                    float qsa = ks_ * fminf(H, gL);
                    Ss = H - qp - qsa;
                    float qsg = qsa * gp;
                    float qs = qsa - qsg;
                    float qg = kg * (Sg + qsg) + qb;
                    Sg = (1.f - kg) * (Sg + qsg) - qb;
                    float q = qp + qs + qg;
                    qwin[j] = q;
                    if (t >= 15) {
                        float c = 0.f;
#pragma unroll
                        for (int kk = 0; kk < 16; ++kk) c += rt[kk] * qwin[(j + 1 + kk) & 15];
                        cv[j] = c;
                    }
                }
            }
#pragma unroll
            for (int j = 0; j < 16; ++j) sred[j*65 + lane] = cv[j];
            asm volatile("s_waitcnt lgkmcnt(0)" ::: "memory");
            {
                int j2 = lane & 15, q2 = lane >> 4;
                float p = 0.f;
#pragma unroll
                for (int i = 0; i < 16; ++i) p += sred[j2*65 + q2*16 + i];
                int tout = tbase + j2 - 15;
                if (tout >= 0 && tout < TOUT)
                    atomicAdd(out + tout*NS + sgrp*4 + q2, p);
            }
        }
        __syncthreads();                // xbuf[(k+1)&1] ready; xbuf[k&1] free
    }
}

// ---------------- launch ----------------
extern "C" void kernel_launch(void* const* d_in, const int* in_sizes, int n_in,
                              void* d_out, int out_size, void* d_ws, size_t ws_size,
                              hipStream_t stream) {
    const float* x   = (const float*)d_in[0];
    const float* xc  = (const float*)d_in[1];
    const float* fw1 = (const float*)d_in[2];
    const float* fb1 = (const float*)d_in[3];
    const float* fw2 = (const float*)d_in[4];
    const float* fb2 = (const float*)d_in[5];
    const float* tw1 = (const float*)d_in[6];
    const float* tb1 = (const float*)d_in[7];
    const float* tw2 = (const float*)d_in[8];
    const float* tb2 = (const float*)d_in[9];
    const float* rw1 = (const float*)d_in[10];
    const float* rb1 = (const float*)d_in[11];
    const float* rw2 = (const float*)d_in[12];
    const float* rb2 = (const float*)d_in[13];
    float* out = (float*)d_out;
    char* ws = (char*)d_ws;

    constexpr size_t OFF_PS    = 0;              //   376,832  [s][368] f32
    constexpr size_t OFF_PLC   = 376832;
    constexpr size_t OFF_E2    = 753664;
    constexpr size_t OFF_PAR   = 1130496;        // 1,835,008
    constexpr size_t OFF_R     = 2965504;        // 4,194,304
    constexpr size_t OFF_W2TT  = 7159808;        //   393,216
    constexpr size_t OFF_H1B   = 7553024;        // 48,234,496 (s-major frag tiles)
    constexpr size_t OFF_PC    = 55787520;       // overlays only now
    constexpr size_t OFF_WLOG  = 200491008;      // 1,835,008
    constexpr size_t OFF_W2TW  = OFF_PC + 0;
    constexpr size_t OFF_W2TR  = OFF_PC + 917504;
    constexpr size_t OFF_H1W   = OFF_PC + 3014656;
    constexpr size_t OFF_H1R   = OFF_PC + 3145728;

    float* psT   = (float*)(ws + OFF_PS);
    float* plcT  = (float*)(ws + OFF_PLC);
    float* e2T   = (float*)(ws + OFF_E2);
    float* par   = (float*)(ws + OFF_PAR);
    float* rbuf  = (float*)(ws + OFF_R);
    u16*   w2tT  = (u16*)(ws + OFF_W2TT);
    u16*   h1b   = (u16*)(ws + OFF_H1B);
    float* wlog  = (float*)(ws + OFF_WLOG);
    u16*   w2tW  = (u16*)(ws + OFF_W2TW);
    u16*   w2tR  = (u16*)(ws + OFF_W2TR);
    u16*   h1W   = (u16*)(ws + OFF_H1W);
    u16*   h1R   = (u16*)(ws + OFF_H1R);

    k_prep     <<<813, 256, 0, stream>>>(x, psT, plcT, e2T, out,
                                         tw2, w2tT, fw2, w2tW, rw2, w2tR,
                                         xc, fw1, fb1, rw1, rb1, h1W, h1R);
    k_mid      <<<3036, 256, 0, stream>>>(h1W, w2tW, fb2, wlog,
                                          h1R, w2tR, rb2, rbuf,
                                          x, xc, tw1, tb1, h1b);
    k_post     <<<256, 256, 0, stream>>>(wlog, par);
    k_scanfuse <<<1024, 128, 0, stream>>>(h1b, w2tT, tb2, psT, plcT, e2T, par, rbuf, out);
}

// Round 14
// 279.591 us; speedup vs baseline: 1.3823x; 1.0039x over previous
//
#include <hip/hip_runtime.h>

// Problem constants
#define NT   365
#define NS   256
#define NH   256
#define NG   32
#define NR   16
#define HID  256
#define NX   38           // 6 + NG
#define M_   (NT*NS)      // 93440
#define TOUT (NT-NR+1)    // 350

typedef __attribute__((ext_vector_type(8))) short short8;
typedef __attribute__((ext_vector_type(4))) short short4v;
typedef __attribute__((ext_vector_type(4))) float floatx4;
typedef unsigned short u16;

__device__ __forceinline__ u16 f2bf(float f) {
    unsigned u = __float_as_uint(f);
    u = (u + 0x7FFFu + ((u >> 16) & 1u)) >> 16;   // RNE
    return (u16)u;
}
__device__ __forceinline__ float sigmoidf_(float x) { return 1.f / (1.f + __expf(-x)); }

// Fragment-tile layout (R17-proven): a 16x32 bf16 MFMA tile is stored as
// 64 lanes x 8 u16 contiguous (1 KB). Element (r, c) lives at
// lane = (r&15) | (((c&31)>>3)<<4), pos = c&7.
// R18: h1b tiles are (s, t-tile): row = t&15, tile idx = (s*23 + tt)*8 + kg
//      (s-stride = 23*8*512 = 94208 u16).
//      w2tT tiles unchanged: tile idx = ntile*8 + kg, ntile = n>>4.

// ---------------- k_prep: pre(365) + cvtT3(416) + mlp1(32) = 813 blocks ----------------
__global__ __launch_bounds__(256) void k_prep(const float* __restrict__ x,
                                              float* __restrict__ psT, float* __restrict__ plcT,
                                              float* __restrict__ e2T,
                                              const float* __restrict__ tw2, u16* __restrict__ w2tT,
                                              const float* __restrict__ fw2, u16* __restrict__ w2tW,
                                              const float* __restrict__ rw2, u16* __restrict__ w2tR,
                                              const float* __restrict__ xc,
                                              const float* __restrict__ wW, const float* __restrict__ bW,
                                              const float* __restrict__ wR, const float* __restrict__ bR,
                                              u16* __restrict__ h1W, u16* __restrict__ h1R) {
    int bx = blockIdx.x, tid = threadIdx.x;
    if (bx < 365) {
        // ---- pre body; outputs transposed [s][368] for fused scan ----
        int m = bx * 256 + tid;          // t = bx, s = tid
        float P  = x[m*6+0], E = x[m*6+1], T1 = x[m*6+2], T2 = x[m*6+3];
        float vf;
        if (T2 <= 0.f)      vf = 1.f;
        else if (T1 >= 0.f) vf = 0.f;
        else {
            float ratio = (T1 + T2) / (T2 - T1);
            ratio = fminf(fmaxf(ratio, -1.f), 1.f);
            vf = acosf(ratio) * (1.f / 3.1415f);
        }
        psT[tid*368 + bx]  = P * vf;
        plcT[tid*368 + bx] = P * (1.f - vf);
        e2T[tid*368 + bx]  = 2.f * E;
    } else if (bx < 781) {
        // ---- cvtT3 body ----
        __shared__ u16 tile[64][65];
        int i2 = bx - 365;
        int bn_ = i2 % 104, bk = i2 / 104;
        const float* w; u16* wt; int N, bn; bool frag;
        if (bn_ < 12)      { w = tw2; wt = w2tT; N = 768;  bn = bn_;      frag = true;  }
        else if (bn_ < 40) { w = fw2; wt = w2tW; N = 1792; bn = bn_ - 12; frag = false; }
        else               { w = rw2; wt = w2tR; N = 4096; bn = bn_ - 40; frag = false; }
        for (int i = tid; i < 64*64; i += 256) {
            int kk = i >> 6, nn = i & 63;
            tile[nn][kk] = f2bf(w[(size_t)(bk*64 + kk)*N + bn*64 + nn]);
        }
        __syncthreads();
        for (int i = tid; i < 64*64; i += 256) {
            int nn = i >> 6, kk = i & 63;
            int n = bn*64 + nn, k = bk*64 + kk;
            if (frag) {
                int ntile = n >> 4, kg = k >> 5;
                int lane2 = (n & 15) | (((k & 31) >> 3) << 4);
                wt[(((size_t)(ntile*8 + kg)) << 9) + (lane2 << 3) + (k & 7)] = tile[nn][kk];
            } else {
                wt[(size_t)n*256 + k] = tile[nn][kk];
            }
        }
    } else {
        // ---- mlp1 body ----
        int b = bx - 781;                       // 0..31: net*16 + grp
        int net = b >> 4, grp = b & 15;
        const float* w1 = net ? wR : wW;
        const float* b1 = net ? bR : bW;
        u16* o = net ? h1R : h1W;
        int s0 = grp * 16, j = tid;
        __shared__ float xs1[16][NG];
        for (int i = j; i < 16*NG; i += 256) xs1[i >> 5][i & 31] = xc[s0*NG + i];
        __syncthreads();
        float acc[16];
        float bb = b1[j];
#pragma unroll
        for (int si = 0; si < 16; ++si) acc[si] = bb;
        for (int g = 0; g < NG; ++g) {
            float w = w1[g*HID + j];
#pragma unroll
            for (int si = 0; si < 16; ++si) acc[si] += xs1[si][g] * w;
        }
#pragma unroll
        for (int si = 0; si < 16; ++si) o[(s0 + si)*256 + j] = f2bf(tanhf(acc[si]));
    }
}

// ---------------- k_mid: gemmS<0>(28) + gemmS<1>(64) + fcT1(2944) = 3036 blocks ----------------
// R26 (kept): fcT1 (8x4)/thread retile, gc-loop unroll 1 (R25's full unroll
// spilled: VGPR 256 + 64MB scratch). smem union (R24).
__global__ __launch_bounds__(256) void k_mid(const u16* __restrict__ h1W, const u16* __restrict__ w2tW,
                                             const float* __restrict__ fb2, float* __restrict__ wlog,
                                             const u16* __restrict__ h1R, const u16* __restrict__ w2tR,
                                             const float* __restrict__ rb2, float* __restrict__ rbuf,
                                             const float* __restrict__ x, const float* __restrict__ xc,
                                             const float* __restrict__ tw1, const float* __restrict__ tb1,
                                             u16* __restrict__ h1b) {
    __shared__ __align__(16) unsigned char smem[16896];   // union: gemmS As+Bs / fcT1 xs->hs
    int bx = blockIdx.x, tid = threadIdx.x;
    if (bx < 92) {
        // ---- gemmS body (mode 0: bx<28, mode 1: else) ----
        int mode, bm, bn, Nn;
        const u16 *A, *B; const float* bias; float* outp;
        if (bx < 28) { mode = 0; bm = bx % 2;        bn = bx / 2;        Nn = 1792; A = h1W; B = w2tW; bias = fb2; outp = wlog; }
        else         { mode = 1; bm = (bx - 28) % 2; bn = (bx - 28) / 2; Nn = 4096; A = h1R; B = w2tR; bias = rb2; outp = rbuf; }
        u16* As = (u16*)smem;              // 8 KB
        u16* Bs = (u16*)(smem + 8192);     // 8 KB
        int wave = tid >> 6, lane = tid & 63;
        floatx4 acc[4][4];
#pragma unroll
        for (int i = 0; i < 4; ++i)
#pragma unroll
            for (int jj = 0; jj < 4; ++jj) acc[i][jj] = (floatx4)(0.f);
        int m0 = bm*128, n0 = bn*128;
        int rA = tid >> 2, cA = (tid & 3) * 8;
        int wm = (wave >> 1)*64, wn = (wave & 1)*64, lr = lane & 15, lq = lane >> 4;
        for (int k0 = 0; k0 < 256; k0 += 32) {
            short8 a0  = *(const short8*)(A + (m0 + rA     )*256 + k0 + cA);
            short8 a1  = *(const short8*)(A + (m0 + rA + 64)*256 + k0 + cA);
            short8 bv0 = *(const short8*)(B + (n0 + rA     )*256 + k0 + cA);
            short8 bv1 = *(const short8*)(B + (n0 + rA + 64)*256 + k0 + cA);
            __syncthreads();
            *(short8*)(As + rA*32 + cA)        = a0;
            *(short8*)(As + (rA + 64)*32 + cA) = a1;
            *(short8*)(Bs + rA*32 + cA)        = bv0;
            *(short8*)(Bs + (rA + 64)*32 + cA) = bv1;
            __syncthreads();
            short8 af[4], bf[4];
#pragma unroll
            for (int i = 0; i < 4; ++i)
                af[i] = *(const short8*)(As + (wm + i*16 + lr)*32 + lq*8);
#pragma unroll
            for (int jj = 0; jj < 4; ++jj)
                bf[jj] = *(const short8*)(Bs + (wn + jj*16 + lr)*32 + lq*8);
#pragma unroll
            for (int i = 0; i < 4; ++i)
#pragma unroll
                for (int jj = 0; jj < 4; ++jj)
                    acc[i][jj] = __builtin_amdgcn_mfma_f32_16x16x32_bf16(af[i], bf[jj], acc[i][jj], 0, 0, 0);
        }
#pragma unroll
        for (int jj = 0; jj < 4; ++jj) {
            int n_glob = n0 + wn + jj*16 + lr;
            float bv = bias[n_glob];
            int hg = (n0 + wn + jj*16) >> 4;
#pragma unroll
            for (int i = 0; i < 4; ++i) {
#pragma unroll
                for (int rr = 0; rr < 4; ++rr) {
                    int m = m0 + wm + i*16 + lq*4 + rr;
                    float v = acc[i][jj][rr] + bv;
                    if (mode == 0) {
                        outp[(size_t)m*Nn + n_glob] = v;
                    } else {
                        v = fmaxf(v, 0.f);
                        float mx = v;
#pragma unroll
                        for (int d = 1; d < 16; d <<= 1) mx = fmaxf(mx, __shfl_xor(mx, d, 64));
                        float e = __expf(v - mx);
                        float sm = e;
#pragma unroll
                        for (int d = 1; d < 16; d <<= 1) sm += __shfl_xor(sm, d, 64);
                        outp[(size_t)m*4096 + hg*16 + lr] = e / sm;
                    }
                }
            }
        }
    } else {
        // ---- fcT1 body: (8 row x 4 col)/thread register tile, unroll-capped ----
        int m0 = (bx - 92) * 32;           // 32 consecutive m = fixed t, 32 consecutive s
        int jg = tid & 63;                 // j-group: cols j0..j0+3
        int rg = tid >> 6;                 // rr-group: rows rr0..rr0+7
        int j0 = jg * 4;
        int rr0 = rg * 8;
        float (*xs)[40] = (float (*)[40])smem;      // 5,120 B (MAC phase; pad cols 38,39 = 0)
        for (int idx = tid; idx < 32*40; idx += 256) {
            int rr = idx / 40, c = idx % 40;
            int m = m0 + rr;
            int mc = m < M_ ? m : M_ - 1;
            int s = mc & (NS - 1);
            float v;
            if (c < 6)        v = x[mc*6 + c];
            else if (c < NX)  v = xc[s*NG + (c - 6)];
            else              v = 0.f;
            xs[rr][c] = v;
        }
        __syncthreads();
        floatx4 bv = *(const floatx4*)(tb1 + j0);
        float acc[8][4];
#pragma unroll
        for (int rp = 0; rp < 8; ++rp)
#pragma unroll
            for (int jj = 0; jj < 4; ++jj) acc[rp][jj] = bv[jj];
        // g = 0..35 in chunks of 4 (ascending order preserved); unroll 1 (R25 lesson)
#pragma unroll 1
        for (int gc = 0; gc < 9; ++gc) {
            floatx4 wv[4];
#pragma unroll
            for (int gq = 0; gq < 4; ++gq)
                wv[gq] = *(const floatx4*)(tw1 + (gc*4 + gq)*HID + j0);
#pragma unroll
            for (int rp = 0; rp < 8; ++rp) {
                floatx4 xv = *(const floatx4*)(&xs[rr0 + rp][gc*4]);
#pragma unroll
                for (int gq = 0; gq < 4; ++gq)
#pragma unroll
                    for (int jj = 0; jj < 4; ++jj)
                        acc[rp][jj] += xv[gq] * wv[gq][jj];
            }
        }
        // remainder g = 36, 37
#pragma unroll 1
        for (int g = 36; g < 38; ++g) {
            floatx4 wv = *(const floatx4*)(tw1 + g*HID + j0);
#pragma unroll
            for (int rp = 0; rp < 8; ++rp) {
                float xv = xs[rr0 + rp][g];
#pragma unroll
                for (int jj = 0; jj < 4; ++jj)
                    acc[rp][jj] += xv * wv[jj];
            }
        }
        __syncthreads();                    // xs reads done -> reuse smem as hs
        u16 (*hs)[264] = (u16 (*)[264])smem;                // 16,896 B (store phase)
#pragma unroll
        for (int rp = 0; rp < 8; ++rp) {
            short4v h4;
#pragma unroll
            for (int jj = 0; jj < 4; ++jj)
                h4[jj] = (short)f2bf(tanhf(acc[rp][jj]));
            *(short4v*)(&hs[rr0 + rp][j0]) = h4;
        }
        __syncthreads();
        // store phase (R21-proven): 1024 chunks of 16B
        int t_  = m0 >> 8;
        int tt_ = t_ >> 4, tr_ = t_ & 15;
        int s0_ = m0 & 255;
#pragma unroll
        for (int p = 0; p < 4; ++p) {
            int cid = p*256 + tid;
            int rr = cid >> 5, c = cid & 31;
            int kg = c >> 2, lh = c & 3;
            int jb = kg*32 + lh*8;
            short8 v = *(const short8*)(&hs[rr][jb]);
            *(short8*)(h1b + (size_t)(s0_ + rr)*94208
                       + (((size_t)tt_*8 + kg) << 9)
                       + ((tr_ | (lh << 4)) << 3)) = v;
        }
    }
}

// ---------------- k_post: fcw_post standalone (256 blocks) ----------------
__global__ __launch_bounds__(256) void k_post(const float* __restrict__ wlog,
                                              float* __restrict__ par) {
    __shared__ float red[256];
    int s = blockIdx.x, j = threadIdx.x;
    const float* L = wlog + (size_t)s*1792;
    float o0 = L[j], o1 = L[256+j], o2 = L[512+j], o3 = L[768+j],
          o4 = L[1024+j], o5 = L[1280+j], o6 = L[1536+j];
    red[j] = o6; __syncthreads();
    for (int st = 128; st > 0; st >>= 1) {
        if (j < st) red[j] = fmaxf(red[j], red[j+st]);
        __syncthreads();
    }
    float mx = red[0]; __syncthreads();
    float e = __expf(o6 - mx);
    red[j] = e; __syncthreads();
    for (int st = 128; st > 0; st >>= 1) {
        if (j < st) red[j] += red[j+st];
        __syncthreads();
    }
    float ga = e / red[0];
    int idx = s*NH + j;
    par[0*65536 + idx] = sigmoidf_(o0);
    par[1*65536 + idx] = sigmoidf_(o1);
    par[2*65536 + idx] = 0.1f * sigmoidf_(o2);
    par[3*65536 + idx] = sigmoidf_(o3);
    par[4*65536 + idx] = __expf(2.f * o4);
    par[5*65536 + idx] = fmaxf(o5, 0.f);
    par[6*65536 + idx] = ga;
}

// ---------------- k_scanfuse: producer-consumer wave-specialized (R22) ----------------
// R27: atomicAdd -> plain stores into per-hb partial planes pout[hb][t][s].
// The per-iteration __syncthreads drains vmcnt(0) INCLUDING atomics; with 16
// same-address contenders deliberately co-located on one XCD (R19 map), the
// atomic drain was the ~6-7K unexplained cycles/iter. Plain stores drain fast
// and contend with nothing. k_final reduces the 16 planes.
__global__ __launch_bounds__(128, 2) void k_scanfuse(const u16* __restrict__ h1b,
                                                     const u16* __restrict__ w2t,
                                                     const float* __restrict__ b2,
                                                     const float* __restrict__ psT,
                                                     const float* __restrict__ plcT,
                                                     const float* __restrict__ e2T,
                                                     const float* __restrict__ par,
                                                     const float* __restrict__ r,
                                                     float* __restrict__ pout) {
    int bx = blockIdx.x;
    int xcd = bx & 7, local = bx >> 3;
    int sgrp = xcd*8 + (local >> 4);
    int hb = local & 15;
    int tid = threadIdx.x;
    int wv = tid >> 6;                 // 0 = producer, 1 = consumer
    int lane = tid & 63;
    int h_idx = lane & 15, s_idx = lane >> 4;
    int s_g = sgrp*4 + s_idx, h_g = hb*16 + h_idx;
    int pidx = s_g*NH + h_g;
    float* po = pout + (size_t)hb*TOUT*NS;

    __shared__ float s_ps[4][368];                 // 5.9 KB (consumer)
    __shared__ float xbuf[2][4*872];               // 27.9 KB (dbuf; stride-18 rows)
    __shared__ float sred[16*65];                  // 4.2 KB (consumer reduce)

    for (int i = tid; i < 4*368; i += 128) {
        int si = i / 368, t = i % 368;
        s_ps[si][t] = (t < NT) ? psT[(sgrp*4 + si)*368 + t] : 0.f;
    }

    short8 Bv[3][8];
    float bias0 = 0.f, bias1 = 0.f, bias2 = 0.f;
    const u16* Ab = h1b + (size_t)(sgrp*4)*94208 + (lane << 3);
    float kp = 0.f, ks_ = 0.f, kg = 0.f, gp = 0.f, gL = 0.f, qb = 0.f;
    float rt[NR];
    float Sf = 0.f, Ss = 0.f, Sg = 0.f;
    float qwin[16];
#pragma unroll
    for (int k = 0; k < 16; ++k) { qwin[k] = 0.f; rt[k] = 0.f; }

    if (wv == 0) {
#pragma unroll
        for (int sg2 = 0; sg2 < 3; ++sg2)
#pragma unroll
            for (int kgi = 0; kgi < 8; ++kgi)
                Bv[sg2][kgi] = *(const short8*)(w2t + (((size_t)((sg2*16 + hb)*8 + kgi)) << 9) + (lane << 3));
        bias0 = b2[0*256 + h_g]; bias1 = b2[1*256 + h_g]; bias2 = b2[2*256 + h_g];
    } else {
        kp = par[pidx]; ks_ = par[65536+pidx]; kg = par[2*65536+pidx];
        gp = par[3*65536+pidx]; gL = par[4*65536+pidx]; qb = par[5*65536+pidx];
        float ga = par[6*65536+pidx];
#pragma unroll
        for (int k = 0; k < NR; ++k) rt[k] = r[(size_t)pidx*NR + k] * ga;
    }

    auto produce = [&](int c, int b) {
        int tbase = c * 16;
        floatx4 acc[4][3];
#pragma unroll
        for (int si = 0; si < 4; ++si)
#pragma unroll
            for (int sg2 = 0; sg2 < 3; ++sg2) acc[si][sg2] = (floatx4)(0.f);
        const u16* An = Ab + (size_t)c*4096;
#pragma unroll
        for (int kgi = 0; kgi < 8; ++kgi) {
            short8 Avk[4];
#pragma unroll
            for (int si = 0; si < 4; ++si)
                Avk[si] = *(const short8*)(An + (size_t)si*94208 + kgi*512);
#pragma unroll
            for (int si = 0; si < 4; ++si)
#pragma unroll
                for (int sg2 = 0; sg2 < 3; ++sg2)
                    acc[si][sg2] = __builtin_amdgcn_mfma_f32_16x16x32_bf16(Avk[si], Bv[sg2][kgi], acc[si][sg2], 0, 0, 0);
        }
        float* xb = &xbuf[b][0];
#pragma unroll
        for (int si = 0; si < 4; ++si) {
            int sg = sgrp*4 + si;
            floatx4 plv = *(const floatx4*)(plcT + sg*368 + tbase + s_idx*4);
            floatx4 e2v = *(const floatx4*)(e2T  + sg*368 + tbase + s_idx*4);
#pragma unroll
            for (int rr = 0; rr < 4; ++rr) {
                int trow = s_idx*4 + rr;
                float v0 = acc[si][0][rr] + bias0;
                float v1 = acc[si][1][rr] + bias1;
                float v2 = acc[si][2][rr] + bias2;
                float pl = plv[rr] * fminf(fmaxf(v0*(1.f/3.f) + 0.5f, 0.f), 1.f);
                float ev = e2v[rr] * fmaxf(v1, 0.f);
                float fm = __expf(v2);
                xb[si*872 + 0*288 + trow*18 + h_idx] = pl;
                xb[si*872 + 1*288 + trow*18 + h_idx] = ev;
                xb[si*872 + 2*288 + trow*18 + h_idx] = fm;
            }
        }
    };

    __syncthreads();                    // s_ps staged
    if (wv == 0) produce(0, 0);         // prologue: chunk 0
    __syncthreads();

    for (int k = 0; k < 23; ++k) {
        if (wv == 0) {
            if (k < 22) produce(k + 1, (k + 1) & 1);
        } else {
            int tbase = k * 16;
            const float* xr = &xbuf[k & 1][0];
            float cv[16];
#pragma unroll
            for (int j = 0; j < 16; ++j) cv[j] = 0.f;
#pragma unroll
            for (int j = 0; j < 16; ++j) {
                int t = tbase + j;
                if (t < NT) {
                    float pl = xr[s_idx*872 + 0*288 + j*18 + h_idx];
                    float ev = xr[s_idx*872 + 1*288 + j*18 + h_idx];
                    float fm = xr[s_idx*872 + 2*288 + j*18 + h_idx];
                    float fs = s_ps[s_idx][t];
                    float qf = fminf(Sf + fs, fm);
                    Sf = fmaxf(Sf + fs - fm, 0.f);
                    float H = fmaxf(Ss + pl + qf - ev, 0.f);
                    float qp = fmaxf(kp * (H - gL), 0.f);
                    float qsa = ks_ * fminf(H, gL);
                    Ss = H - qp - qsa;
                    float qsg = qsa * gp;
                    float qs = qsa - qsg;
                    float qg = kg * (Sg + qsg) + qb;
                    Sg = (1.f - kg) * (Sg + qsg) - qb;
                    float q = qp + qs + qg;
                    qwin[j] = q;
                    if (t >= 15) {
                        float c = 0.f;
#pragma unroll
                        for (int kk = 0; kk < 16; ++kk) c += rt[kk] * qwin[(j + 1 + kk) & 15];
                        cv[j] = c;
                    }
                }
            }
#pragma unroll
            for (int j = 0; j < 16; ++j) sred[j*65 + lane] = cv[j];
            asm volatile("s_waitcnt lgkmcnt(0)" ::: "memory");
            {
                int j2 = lane & 15, q2 = lane >> 4;
                float p = 0.f;
#pragma unroll
                for (int i = 0; i < 16; ++i) p += sred[j2*65 + q2*16 + i];
                int tout = tbase + j2 - 15;
                if (tout >= 0 && tout < TOUT)
                    po[tout*NS + sgrp*4 + q2] = p;     // plain store, no contention
            }
        }
        __syncthreads();                // xbuf[(k+1)&1] ready; xbuf[k&1] free
    }
}

// ---------------- k_final: reduce 16 hb partial planes -> out (350 blocks) ----------------
__global__ __launch_bounds__(256) void k_final(const float* __restrict__ pout,
                                               float* __restrict__ out) {
    int t = blockIdx.x, s = threadIdx.x;
    float a = 0.f;
#pragma unroll
    for (int hb = 0; hb < 16; ++hb)
        a += pout[(size_t)hb*TOUT*NS + t*NS + s];
    out[t*NS + s] = a;
}

// ---------------- launch ----------------
extern "C" void kernel_launch(void* const* d_in, const int* in_sizes, int n_in,
                              void* d_out, int out_size, void* d_ws, size_t ws_size,
                              hipStream_t stream) {
    const float* x   = (const float*)d_in[0];
    const float* xc  = (const float*)d_in[1];
    const float* fw1 = (const float*)d_in[2];
    const float* fb1 = (const float*)d_in[3];
    const float* fw2 = (const float*)d_in[4];
    const float* fb2 = (const float*)d_in[5];
    const float* tw1 = (const float*)d_in[6];
    const float* tb1 = (const float*)d_in[7];
    const float* tw2 = (const float*)d_in[8];
    const float* tb2 = (const float*)d_in[9];
    const float* rw1 = (const float*)d_in[10];
    const float* rb1 = (const float*)d_in[11];
    const float* rw2 = (const float*)d_in[12];
    const float* rb2 = (const float*)d_in[13];
    float* out = (float*)d_out;
    char* ws = (char*)d_ws;

    constexpr size_t OFF_PS    = 0;              //   376,832  [s][368] f32
    constexpr size_t OFF_PLC   = 376832;
    constexpr size_t OFF_E2    = 753664;
    constexpr size_t OFF_PAR   = 1130496;        // 1,835,008
    constexpr size_t OFF_R     = 2965504;        // 4,194,304
    constexpr size_t OFF_W2TT  = 7159808;        //   393,216
    constexpr size_t OFF_H1B   = 7553024;        // 48,234,496 (s-major frag tiles)
    constexpr size_t OFF_PC    = 55787520;       // overlay region (dead after k_mid)
    constexpr size_t OFF_WLOG  = 200491008;      // 1,835,008
    constexpr size_t OFF_W2TW  = OFF_PC + 0;
    constexpr size_t OFF_W2TR  = OFF_PC + 917504;
    constexpr size_t OFF_H1W   = OFF_PC + 3014656;
    constexpr size_t OFF_H1R   = OFF_PC + 3145728;
    constexpr size_t OFF_POUT  = OFF_PC + 4194304;   // 5,734,400 B (16*350*256 f32)

    float* psT   = (float*)(ws + OFF_PS);
    float* plcT  = (float*)(ws + OFF_PLC);
    float* e2T   = (float*)(ws + OFF_E2);
    float* par   = (float*)(ws + OFF_PAR);
    float* rbuf  = (float*)(ws + OFF_R);
    u16*   w2tT  = (u16*)(ws + OFF_W2TT);
    u16*   h1b   = (u16*)(ws + OFF_H1B);
    float* wlog  = (float*)(ws + OFF_WLOG);
    u16*   w2tW  = (u16*)(ws + OFF_W2TW);
    u16*   w2tR  = (u16*)(ws + OFF_W2TR);
    u16*   h1W   = (u16*)(ws + OFF_H1W);
    u16*   h1R   = (u16*)(ws + OFF_H1R);
    float* pout  = (float*)(ws + OFF_POUT);

    k_prep     <<<813, 256, 0, stream>>>(x, psT, plcT, e2T,
                                         tw2, w2tT, fw2, w2tW, rw2, w2tR,
                                         xc, fw1, fb1, rw1, rb1, h1W, h1R);
    k_mid      <<<3036, 256, 0, stream>>>(h1W, w2tW, fb2, wlog,
                                          h1R, w2tR, rb2, rbuf,
                                          x, xc, tw1, tb1, h1b);
    k_post     <<<256, 256, 0, stream>>>(wlog, par);
    k_scanfuse <<<1024, 128, 0, stream>>>(h1b, w2tT, tb2, psT, plcT, e2T, par, rbuf, pout);
    k_final    <<<TOUT, 256, 0, stream>>>(pout, out);
}